// Round 1
// baseline (587.888 us; speedup 1.0000x reference)
//
#include <hip/hip_runtime.h>
#include <math.h>

#define NB 512
#define NS 1024
#define NT 52
#define TAG_START 50
#define TAG_END 51

// broadcast lane l's value of x to all lanes (compile-time l -> v_readlane_b32)
__device__ __forceinline__ float lane_bcast(float x, int l) {
  return __int_as_float(__builtin_amdgcn_readlane(__float_as_int(x), l));
}

extern "C" __global__ void __launch_bounds__(64)
crf_batch_kernel(const float* __restrict__ feats,
                 const unsigned char* __restrict__ mask_u8,
                 const int* __restrict__ tags,
                 const float* __restrict__ trans,
                 double* __restrict__ scores)
{
  const int b = blockIdx.x;
  const int lane = threadIdx.x;

  // ---- detect mask dtype: bool (1 byte) vs int32 (4 byte) ----
  // Every sequence has length >= 1, so under the byte hypothesis
  // mask_u8[i*NS] == 1 for every row i. If any differs -> int32 layout.
  int bad = 0;
  for (int i = lane; i < NB; i += 64) bad |= (mask_u8[(size_t)i * NS] != 1u);
  const bool int_mode = (__any(bad) != 0);

  // ---- sequence length of row b (prefix mask sum) ----
  int len = 0;
  if (int_mode) {
    const int* mi = (const int*)mask_u8;
    for (int s = lane; s < NS; s += 64) len += mi[b * NS + s];
  } else {
    for (int s = lane; s < NS; s += 64) len += (int)mask_u8[b * NS + s];
  }
  #pragma unroll
  for (int off = 32; off > 0; off >>= 1) len += __shfl_xor(len, off, 64);

  // ---- per-lane column j of M = exp(transitions): Mcol[i] = exp(T[i][j]) ----
  const int j = (lane < NT) ? lane : 0;
  float Mcol[NT];
  #pragma unroll
  for (int i = 0; i < NT; ++i) Mcol[i] = __expf(trans[i * NT + j]);
  if (lane >= NT) {
    #pragma unroll
    for (int i = 0; i < NT; ++i) Mcol[i] = 0.f;   // idle lanes contribute nothing
  }

  const float* fb = feats + (size_t)b * NS * NT;

  // ---- init (s = 0): part0[j] = f0[j] + trans[START][j]; v = exp(part0 - c0) ----
  float p0 = (lane < NT) ? (fb[lane] + trans[TAG_START * NT + lane]) : -1e30f;
  float c0 = p0;
  #pragma unroll
  for (int off = 32; off > 0; off >>= 1) c0 = fmaxf(c0, __shfl_xor(c0, off, 64));
  float v = (lane < NT) ? __expf(p0 - c0) : 0.f;
  int kacc = 0;  // accumulated power-of-2 normalizer (exact)

  // ---- forward recursion, exp domain: v <- exp(f) * (M^T v), renorm by 2^-K ----
  const float* frow = fb + j;
  float fA = frow[1 * NT];     // S rows always exist; prefetch depth 2
  float fB = frow[2 * NT];
  for (int s = 1; s < len; ++s) {
    float f = fA;
    fA = fB;
    int sp = (s + 2 < NS) ? (s + 2) : (NS - 1);
    fB = frow[sp * NT];

    float a0 = 0.f, a1 = 0.f, a2 = 0.f, a3 = 0.f;
    #pragma unroll
    for (int i = 0; i < NT; i += 4) {
      a0 = fmaf(lane_bcast(v, i + 0), Mcol[i + 0], a0);
      a1 = fmaf(lane_bcast(v, i + 1), Mcol[i + 1], a1);
      a2 = fmaf(lane_bcast(v, i + 2), Mcol[i + 2], a2);
      a3 = fmaf(lane_bcast(v, i + 3), Mcol[i + 3], a3);
    }
    float nv = __expf(f) * ((a0 + a1) + (a2 + a3));

    // renormalize all lanes by 2^-K where K = exponent of lane 0's value.
    // cross-lane spread is bounded (~2^18), so no overflow/underflow risk.
    float n0 = lane_bcast(nv, 0);
    int K = ((__float_as_int(n0) >> 23) & 0xff) - 127;
    v = ldexpf(nv, -K);
    kacc += K;
  }

  // ---- final: forward_b = c0 + kacc*ln2 + log(sum_i v[i] * M[i][END]) ----
  float e0 = 0.f, e1 = 0.f, e2 = 0.f, e3 = 0.f;
  #pragma unroll
  for (int i = 0; i < NT; i += 4) {
    e0 = fmaf(lane_bcast(v, i + 0), Mcol[i + 0], e0);
    e1 = fmaf(lane_bcast(v, i + 1), Mcol[i + 1], e1);
    e2 = fmaf(lane_bcast(v, i + 2), Mcol[i + 2], e2);
    e3 = fmaf(lane_bcast(v, i + 3), Mcol[i + 3], e3);
  }
  float fin  = __logf((e0 + e1) + (e2 + e3));   // valid on lane j == END
  float finU = lane_bcast(fin, TAG_END);
  double fwd = (double)c0 + (double)kacc * 0.6931471805599453 + (double)finU;

  // ---- gold path score ----
  float g = 0.f;
  for (int s = lane; s < len; s += 64) {
    int tg = tags[b * NS + s];
    int pv = (s == 0) ? TAG_START : tags[b * NS + s - 1];
    g += fb[s * NT + tg] + trans[pv * NT + tg];
  }
  #pragma unroll
  for (int off = 32; off > 0; off >>= 1) g += __shfl_xor(g, off, 64);
  int lastTag = tags[b * NS + (len - 1)];
  double gold = (double)g + (double)trans[lastTag * NT + TAG_END];

  if (lane == 0) scores[b] = fwd - gold;
}

extern "C" __global__ void __launch_bounds__(512)
crf_reduce_kernel(const double* __restrict__ scores, float* __restrict__ out)
{
  __shared__ double sh[8];
  int t = threadIdx.x;
  double x = scores[t];
  #pragma unroll
  for (int off = 32; off > 0; off >>= 1) x += __shfl_xor(x, off, 64);
  if ((t & 63) == 0) sh[t >> 6] = x;
  __syncthreads();
  if (t == 0) {
    double tot = 0.0;
    #pragma unroll
    for (int w = 0; w < 8; ++w) tot += sh[w];
    out[0] = (float)tot;
  }
}

extern "C" void kernel_launch(void* const* d_in, const int* in_sizes, int n_in,
                              void* d_out, int out_size, void* d_ws, size_t ws_size,
                              hipStream_t stream) {
  const float*         feats = (const float*)d_in[0];
  const unsigned char* mask  = (const unsigned char*)d_in[1];
  const int*           tags  = (const int*)d_in[2];
  const float*         trans = (const float*)d_in[3];
  double* scores = (double*)d_ws;   // 512 doubles = 4 KB scratch

  crf_batch_kernel<<<NB, 64, 0, stream>>>(feats, mask, tags, trans, scores);
  crf_reduce_kernel<<<1, 512, 0, stream>>>(scores, (float*)d_out);
}